// Round 1
// baseline (51.233 us; speedup 1.0000x reference)
//
#include <hip/hip_runtime.h>

// Problem constants
#define GG 16
#define HH 8
#define NAH 128   // nodes per graph per side
#define HDIM 32
#define DD 256

// ws layout (float offsets)
#define WS_X1      0
#define WS_X2      524288      // 2048*256
#define WS_ROWSUM  1048576     // G*H*128 = 16384
#define WS_COLHALF 1064960     // G*H*2*128 = 32768

__device__ __forceinline__ float tanh_pre(float e) {
    // e = (2*log2e) * x  already applied; returns tanh(x)
    e = fminf(fmaxf(e, -30.f), 30.f);
    float t = __builtin_amdgcn_exp2f(e);
    return (t - 1.f) * __builtin_amdgcn_rcpf(t + 1.f);
}

// ---------------- K1: x = In @ W^T + bias  (both matrices) ----------------
// grid 512: blocks 0..255 -> A/W1/b1 -> ws_x1 ; 256..511 -> B/W2/b2 -> ws_x2
// block: 8 rows x 256 cols, 256 threads (thread = col)
__global__ __launch_bounds__(256) void k1_gemm(
        const float* __restrict__ A, const float* __restrict__ B,
        const float* __restrict__ W1, const float* __restrict__ b1,
        const float* __restrict__ W2, const float* __restrict__ b2,
        float* __restrict__ ws) {
    const int bid = blockIdx.x;
    const int mat = bid >> 8;
    const int r0 = (bid & 255) * 8;
    const float* In = mat ? B : A;
    const float* W  = mat ? W2 : W1;
    const float* bs = mat ? b2 : b1;
    float* Out = ws + (mat ? WS_X2 : WS_X1);

    __shared__ float a_lds[8 * 256];
    const int t = threadIdx.x;
    {
        const float4* src = (const float4*)(In + r0 * 256);
        float4* dst = (float4*)a_lds;
        dst[t] = src[t];
        dst[t + 256] = src[t + 256];
    }
    __syncthreads();

    const int col = t;
    const float4* wr = (const float4*)(W + col * 256);
    float acc[8];
    #pragma unroll
    for (int r = 0; r < 8; ++r) acc[r] = 0.f;
    #pragma unroll 4
    for (int d4 = 0; d4 < 64; ++d4) {
        float4 wv = wr[d4];
        #pragma unroll
        for (int r = 0; r < 8; ++r) {
            float4 av = ((const float4*)(a_lds + r * 256))[d4];  // wave-broadcast
            acc[r] = fmaf(wv.x, av.x, acc[r]);
            acc[r] = fmaf(wv.y, av.y, acc[r]);
            acc[r] = fmaf(wv.z, av.z, acc[r]);
            acc[r] = fmaf(wv.w, av.w, acc[r]);
        }
    }
    const float bv = bs[col];
    #pragma unroll
    for (int r = 0; r < 8; ++r)
        Out[(r0 + r) * 256 + col] = acc[r] + bv;
}

// ---------------- K2: att row/col sums ----------------
// grid 256: block = (gh, half). half selects 64 i-rows. 512 threads:
//   j = tid&127 (column), iset = tid>>7 (row subset of 16), wave = tid>>6.
__global__ __launch_bounds__(512) void k2_att(float* __restrict__ ws,
                                              const float* __restrict__ q) {
    const int bid = blockIdx.x;
    const int gh = bid >> 1;
    const int half = bid & 1;
    const int tid = threadIdx.x;
    const int j = tid & 127;
    const int iset = tid >> 7;
    const int wv = tid >> 6;
    const int lane = tid & 63;

    __shared__ float lx1[64 * 32];      // scaled by 2*log2e
    __shared__ float lx2[128 * 36];     // padded stride 36 (bank spread)
    __shared__ float rowpart[8][16];
    __shared__ float colpart[4][128];

    const float* x1t = ws + WS_X1 + gh * 4096 + half * 2048;
    const float* x2t = ws + WS_X2 + gh * 4096;
    {
        const float4* s1 = (const float4*)x1t;
        float4 v = s1[tid];
        const float c = 2.8853900817779268f;  // 2*log2(e)
        v.x *= c; v.y *= c; v.z *= c; v.w *= c;
        ((float4*)lx1)[tid] = v;
        const float4* s2 = (const float4*)x2t;
        #pragma unroll
        for (int p = 0; p < 2; ++p) {
            int vI = tid + p * 512;
            int row = vI >> 3, c4 = vI & 7;
            *(float4*)(lx2 + row * 36 + c4 * 4) = s2[vI];
        }
    }
    __syncthreads();

    // x2 row j -> registers (one-time, minor bank aliasing ok)
    float xr[32];
    #pragma unroll
    for (int k4 = 0; k4 < 8; ++k4) {
        float4 v = *(const float4*)(lx2 + j * 36 + k4 * 4);
        xr[k4*4+0] = v.x; xr[k4*4+1] = v.y; xr[k4*4+2] = v.z; xr[k4*4+3] = v.w;
    }

    float colacc = 0.f;
    for (int r = 0; r < 16; ++r) {
        const float* ar = lx1 + (iset * 16 + r) * 32;   // wave-uniform -> broadcast
        float att = 0.f;
        #pragma unroll
        for (int k4 = 0; k4 < 8; ++k4) {
            float4 a4 = *(const float4*)(ar + k4 * 4);
            att = fmaf(tanh_pre(a4.x * xr[k4*4+0]), q[k4*4+0], att);
            att = fmaf(tanh_pre(a4.y * xr[k4*4+1]), q[k4*4+1], att);
            att = fmaf(tanh_pre(a4.z * xr[k4*4+2]), q[k4*4+2], att);
            att = fmaf(tanh_pre(a4.w * xr[k4*4+3]), q[k4*4+3], att);
        }
        colacc += att;
        float rs = att;
        #pragma unroll
        for (int m = 32; m >= 1; m >>= 1) rs += __shfl_xor(rs, m);
        if (lane == 0) rowpart[wv][r] = rs;
    }
    colpart[iset][j] = colacc;
    __syncthreads();

    if (tid < 64) {
        const int is2 = tid >> 4, r2 = tid & 15;
        float v = rowpart[is2 * 2][r2] + rowpart[is2 * 2 + 1][r2];
        ws[WS_ROWSUM + gh * 128 + half * 64 + tid] = v;
    }
    if (tid < 128) {
        float v = colpart[0][tid] + colpart[1][tid] + colpart[2][tid] + colpart[3][tid];
        ws[WS_COLHALF + (gh * 2 + half) * 128 + tid] = v;
    }
}

// ---------------- K3: softmaxes + weighted sums -> out ----------------
// grid 128 (one per gh), 256 threads: side = tid>>7 (0:A,1:B), u = tid&127
__global__ __launch_bounds__(256) void k3_out(const float* __restrict__ ws,
                                              float* __restrict__ out) {
    const int gh = blockIdx.x;
    const int g = gh >> 3, h = gh & 7;
    const int tid = threadIdx.x;
    const int side = tid >> 7;
    const int u = tid & 127;
    const int w2 = (u >> 6) & 1;
    const int lane = tid & 63;

    __shared__ float warr[2][128];
    __shared__ float red[4];
    __shared__ float red2[4];
    __shared__ float part[2][4][32];

    float m;
    if (side == 0) {
        m = ws[WS_ROWSUM + gh * 128 + u] * 0.0078125f;           // /128 (mean over j)
    } else {
        m = (ws[WS_COLHALF + (gh * 2) * 128 + u] +
             ws[WS_COLHALF + (gh * 2 + 1) * 128 + u]) * 0.0078125f;  // mean over i
    }

    float mx = m;
    #pragma unroll
    for (int s = 32; s >= 1; s >>= 1) mx = fmaxf(mx, __shfl_xor(mx, s));
    if (lane == 0) red[side * 2 + w2] = mx;
    __syncthreads();
    mx = fmaxf(red[side * 2], red[side * 2 + 1]);

    float e = __builtin_amdgcn_exp2f((m - mx) * 1.4426950408889634f);
    float sm = e;
    #pragma unroll
    for (int s = 32; s >= 1; s >>= 1) sm += __shfl_xor(sm, s);
    if (lane == 0) red2[side * 2 + w2] = sm;
    __syncthreads();
    const float tot = red2[side * 2] + red2[side * 2 + 1];
    warr[side][u] = e * __builtin_amdgcn_rcpf(tot);
    __syncthreads();

    const int k = u & 31, is = u >> 5;
    const float* xt = ws + (side ? WS_X2 : WS_X1) + gh * 4096;
    float p = 0.f;
    #pragma unroll 4
    for (int r = 0; r < 32; ++r)
        p = fmaf(xt[(is * 32 + r) * 32 + k], warr[side][is * 32 + r], p);
    part[side][is][k] = p;
    __syncthreads();
    if (u < 32) {
        float o = part[side][0][u] + part[side][1][u] + part[side][2][u] + part[side][3][u];
        out[g * 512 + side * 256 + h * 32 + u] = o;
    }
}

extern "C" void kernel_launch(void* const* d_in, const int* in_sizes, int n_in,
                              void* d_out, int out_size, void* d_ws, size_t ws_size,
                              hipStream_t stream) {
    const float* A  = (const float*)d_in[0];
    const float* B  = (const float*)d_in[2];
    const float* W1 = (const float*)d_in[4];
    const float* b1 = (const float*)d_in[5];
    const float* W2 = (const float*)d_in[6];
    const float* b2 = (const float*)d_in[7];
    const float* q  = (const float*)d_in[8];
    float* ws  = (float*)d_ws;
    float* out = (float*)d_out;

    k1_gemm<<<512, 256, 0, stream>>>(A, B, W1, b1, W2, b2, ws);
    k2_att<<<256, 512, 0, stream>>>(ws, q);
    k3_out<<<128, 256, 0, stream>>>(ws, out);
}

// Round 2
// 47.926 us; speedup vs baseline: 1.0690x; 1.0690x over previous
//
#include <hip/hip_runtime.h>

// Problem constants: G=16, H=8, N=128/side, HD=32, D=256
#define C2L2E 2.8853900817779268f   // 2*log2(e)

// ws layout (float offsets)
#define WS_X1      0           // 2048*256 unscaled x1
#define WS_X2      524288      // 2048*256 x2
#define WS_X1S     1048576     // 2048*256 x1 * 2log2e
#define WS_ROWSUM  1572864     // G*H*128
#define WS_COLQ    1589248     // G*H*4*128 quarter col partials

// ---------------- K1: x = In @ W^T + bias ----------------
// grid 512: bid<256 -> A/W1/b1 -> x1 (+x1s scaled); else B/W2/b2 -> x2.
// 256 threads = one output column each, 8 rows per thread.
// A-row operand read via wave-uniform global loads (s_load pipe, no LDS).
__global__ __launch_bounds__(256) void k1_gemm(
        const float* __restrict__ A, const float* __restrict__ B,
        const float* __restrict__ W1, const float* __restrict__ b1,
        const float* __restrict__ W2, const float* __restrict__ b2,
        float* __restrict__ x1, float* __restrict__ x1s, float* __restrict__ x2) {
    const int bid = blockIdx.x;
    const int mat = bid >> 8;
    const int r0 = (bid & 255) * 8;
    const float* In = mat ? B : A;
    const float* W  = mat ? W2 : W1;
    const float* bs = mat ? b2 : b1;

    const int c = threadIdx.x;
    const float4* wr = (const float4*)(W + (size_t)c * 256);
    const float4* a0 = (const float4*)(In + (size_t)r0 * 256);  // wave-uniform base

    float acc[8];
    #pragma unroll
    for (int r = 0; r < 8; ++r) acc[r] = 0.f;

    #pragma unroll 2
    for (int d4 = 0; d4 < 64; ++d4) {
        float4 wv = wr[d4];
        #pragma unroll
        for (int r = 0; r < 8; ++r) {
            float4 av = a0[r * 64 + d4];     // uniform -> s_load
            acc[r] = fmaf(wv.x, av.x, acc[r]);
            acc[r] = fmaf(wv.y, av.y, acc[r]);
            acc[r] = fmaf(wv.z, av.z, acc[r]);
            acc[r] = fmaf(wv.w, av.w, acc[r]);
        }
    }
    const float bv = bs[c];
    if (mat == 0) {
        #pragma unroll
        for (int r = 0; r < 8; ++r) {
            float v = acc[r] + bv;
            x1[(size_t)(r0 + r) * 256 + c]  = v;
            x1s[(size_t)(r0 + r) * 256 + c] = v * C2L2E;
        }
    } else {
        #pragma unroll
        for (int r = 0; r < 8; ++r)
            x2[(size_t)(r0 + r) * 256 + c] = acc[r] + bv;
    }
}

// ---------------- K2: S-sums of q·tanh(x1*x2) ----------------
// att(i,j) = sum_k q_k*tanh(x1_ik*x2_jk) = Qsum + S(i,j), S = sum_k (-2q_k)/(t+1),
// t = exp2(2log2e*x1*x2). Qsum is a uniform logit shift -> softmax-invariant -> dropped.
// grid 512: block=(gh, quarter of 32 i-rows). 512 threads: j=tid&127, iset=tid>>7.
__global__ __launch_bounds__(512, 4) void k2_att(
        const float* __restrict__ x1v, const float* __restrict__ x2v,
        const float* __restrict__ q,
        float* __restrict__ rowsum, float* __restrict__ colq) {
    const int bid = blockIdx.x;
    const int gh = bid >> 2;
    const int qd = bid & 3;
    const int tid = threadIdx.x;
    const int j = tid & 127;
    const int iset = __builtin_amdgcn_readfirstlane(tid >> 7);  // wave-uniform 0..3

    __shared__ float Smat[32 * 132];
    __shared__ float colp[4][128];
    __shared__ float red8[32][8];

    // x2 row j -> registers (per-lane global loads, one-time)
    float xr[32];
    {
        const float4* xp = (const float4*)(x2v + (size_t)gh * 4096 + (size_t)j * 32);
        #pragma unroll
        for (int k4 = 0; k4 < 8; ++k4) {
            float4 v = xp[k4];
            xr[k4*4+0] = v.x; xr[k4*4+1] = v.y; xr[k4*4+2] = v.z; xr[k4*4+3] = v.w;
        }
    }
    // qt = -2q
    float qt[32];
    #pragma unroll
    for (int k = 0; k < 32; ++k) qt[k] = -2.0f * q[k];

    const float* x1base = x1v + (size_t)gh * 4096 + (size_t)(qd * 32 + iset * 8) * 32;
    float colacc = 0.f;

    for (int r = 0; r < 8; ++r) {
        const float4* ap = (const float4*)(x1base + r * 32);  // uniform -> s_load
        float a[32];
        #pragma unroll
        for (int k4 = 0; k4 < 8; ++k4) {
            float4 v = ap[k4];
            a[k4*4+0] = v.x; a[k4*4+1] = v.y; a[k4*4+2] = v.z; a[k4*4+3] = v.w;
        }
        float S0 = 0.f, S1 = 0.f;
        #pragma unroll
        for (int kp = 0; kp < 16; ++kp) {
            float p0 = a[2*kp]   * xr[2*kp];
            float p1 = a[2*kp+1] * xr[2*kp+1];
            float d0 = __builtin_amdgcn_exp2f(fminf(p0, 60.f)) + 1.f;
            float d1 = __builtin_amdgcn_exp2f(fminf(p1, 60.f)) + 1.f;
            float rD = __builtin_amdgcn_rcpf(d0 * d1);
            float U  = fmaf(qt[2*kp+1], d0, qt[2*kp] * d1);
            if (kp & 1) S1 = fmaf(U, rD, S1); else S0 = fmaf(U, rD, S0);
        }
        float S = S0 + S1;
        colacc += S;
        Smat[(iset * 8 + r) * 132 + j] = S;
    }
    colp[iset][j] = colacc;
    __syncthreads();

    if (tid < 256) {                       // rowsum stage 1: 16-chunk sums
        const int row = tid >> 3, seg = tid & 7;
        const float4* sp = (const float4*)(Smat + row * 132 + seg * 16);
        float4 v0 = sp[0], v1 = sp[1], v2 = sp[2], v3 = sp[3];
        red8[row][seg] = (v0.x+v0.y+v0.z+v0.w) + (v1.x+v1.y+v1.z+v1.w)
                       + (v2.x+v2.y+v2.z+v2.w) + (v3.x+v3.y+v3.z+v3.w);
    }
    __syncthreads();
    if (tid < 32) {
        float s = 0.f;
        #pragma unroll
        for (int m = 0; m < 8; ++m) s += red8[tid][m];
        rowsum[gh * 128 + qd * 32 + tid] = s;
    }
    if (tid < 128) {
        colq[(size_t)bid * 128 + tid] =
            colp[0][tid] + colp[1][tid] + colp[2][tid] + colp[3][tid];
    }
}

// ---------------- K3: softmaxes + weighted sums -> out ----------------
// grid 128 (one per gh), 256 threads: side=tid>>7 (0:A,1:B), u=tid&127
__global__ __launch_bounds__(256) void k3_out(
        const float* __restrict__ x1v, const float* __restrict__ x2v,
        const float* __restrict__ rowsum, const float* __restrict__ colq,
        float* __restrict__ out) {
    const int gh = blockIdx.x;
    const int g = gh >> 3, h = gh & 7;
    const int tid = threadIdx.x;
    const int side = tid >> 7;
    const int u = tid & 127;
    const int w2 = (u >> 6) & 1;
    const int lane = tid & 63;

    __shared__ float warr[2][128];
    __shared__ float red[4];
    __shared__ float red2[4];
    __shared__ float part[2][4][32];

    float m;
    if (side == 0) {
        m = rowsum[gh * 128 + u] * 0.0078125f;
    } else {
        m = (colq[(size_t)(gh * 4 + 0) * 128 + u] + colq[(size_t)(gh * 4 + 1) * 128 + u] +
             colq[(size_t)(gh * 4 + 2) * 128 + u] + colq[(size_t)(gh * 4 + 3) * 128 + u]) * 0.0078125f;
    }

    float mx = m;
    #pragma unroll
    for (int s = 32; s >= 1; s >>= 1) mx = fmaxf(mx, __shfl_xor(mx, s));
    if (lane == 0) red[side * 2 + w2] = mx;
    __syncthreads();
    mx = fmaxf(red[side * 2], red[side * 2 + 1]);

    float e = __builtin_amdgcn_exp2f((m - mx) * 1.4426950408889634f);
    float sm = e;
    #pragma unroll
    for (int s = 32; s >= 1; s >>= 1) sm += __shfl_xor(sm, s);
    if (lane == 0) red2[side * 2 + w2] = sm;
    __syncthreads();
    const float tot = red2[side * 2] + red2[side * 2 + 1];
    warr[side][u] = e * __builtin_amdgcn_rcpf(tot);
    __syncthreads();

    const int k = u & 31, is = u >> 5;
    const float* xt = (side ? x2v : x1v) + (size_t)gh * 4096;
    float p = 0.f;
    #pragma unroll 4
    for (int r = 0; r < 32; ++r)
        p = fmaf(xt[(is * 32 + r) * 32 + k], warr[side][is * 32 + r], p);
    part[side][is][k] = p;
    __syncthreads();
    if (u < 32) {
        float o = part[side][0][u] + part[side][1][u] + part[side][2][u] + part[side][3][u];
        out[g * 512 + side * 256 + h * 32 + u] = o;
    }
}

extern "C" void kernel_launch(void* const* d_in, const int* in_sizes, int n_in,
                              void* d_out, int out_size, void* d_ws, size_t ws_size,
                              hipStream_t stream) {
    const float* A  = (const float*)d_in[0];
    const float* B  = (const float*)d_in[2];
    const float* W1 = (const float*)d_in[4];
    const float* b1 = (const float*)d_in[5];
    const float* W2 = (const float*)d_in[6];
    const float* b2 = (const float*)d_in[7];
    const float* q  = (const float*)d_in[8];
    float* ws  = (float*)d_ws;
    float* out = (float*)d_out;

    float* x1  = ws + WS_X1;
    float* x2  = ws + WS_X2;
    float* x1s = ws + WS_X1S;
    float* rs  = ws + WS_ROWSUM;
    float* cq  = ws + WS_COLQ;

    k1_gemm<<<512, 256, 0, stream>>>(A, B, W1, b1, W2, b2, x1, x1s, x2);
    k2_att<<<512, 512, 0, stream>>>(x1s, x2, q, rs, cq);
    k3_out<<<128, 256, 0, stream>>>(x1, x2, rs, cq, out);
}